// Round 5
// baseline (201.239 us; speedup 1.0000x reference)
//
#include <hip/hip_runtime.h>

// Geometry: M=N=128, padded S=256. Two volumes (b*d=2).
// A: [v][z<128][y:256][x:256] complex fp32 = 134 MB total.
// B (packed): [v][z<128][y:256][x<128] complex fp32 = 67 MB total.
// Forward pass order: x-FFT -> z-FFT (y still <128: half traffic) -> y-FFT.
static constexpr size_t VS   = 8388608;  // 128*256*256 per volume (A)
static constexpr int    ZSTR = 65536;    // 256*256
static constexpr int    YSTR = 256;
static constexpr size_t VSB  = 4194304;  // 128*256*128 per volume (B)
static constexpr int    BZS  = 32768;    // 256*128
static constexpr int    BYS  = 128;
static constexpr int    LSTR = 261;      // LDS line stride (vf2); 5*l mod 16 spreads bank-pairs

typedef float vf2 __attribute__((ext_vector_type(2)));  // complex: .x=re, .y=im -> v_pk_* f32

__device__ __forceinline__ vf2 cmul(vf2 a, vf2 b){
    vf2 asw; asw.x = -a.y; asw.y = a.x;       // i*a
    return a*b.x + asw*b.y;                   // pk_mul + pk_fma
}

constexpr int BREV(int k){ return ((k&1)<<3)|((k&2)<<1)|((k&4)>>1)|((k&8)>>3); }

// Butterfly: a' = a+b; b' = (a-b) rotated by (c,s). Packed VOP3P.
__device__ __forceinline__ void bf(vf2& a, vf2& b, float c, float s){
    vf2 sum = a + b;
    vf2 dif = a - b;
    vf2 dsw; dsw.x = -dif.y; dsw.y = dif.x;   // i*dif
    b = dif*c + dsw*s;
    a = sum;
}

// Fully-unrolled 16-pt DIF FFT, natural input, bit-reversed output: X[k] = r[BREV(k)].
template<int DIR>
__device__ __forceinline__ void fft16(vf2 r[16]){
    constexpr float D = (float)DIR;
    constexpr float C16[8] = {1.f, 0.92387953f, 0.70710678f, 0.38268343f, 0.f, -0.38268343f, -0.70710678f, -0.92387953f};
    constexpr float S16[8] = {0.f, 0.38268343f, 0.70710678f, 0.92387953f, 1.f, 0.92387953f, 0.70710678f, 0.38268343f};
#pragma unroll
    for (int j = 0; j < 8; ++j) bf(r[j], r[j+8], C16[j], D*S16[j]);
    constexpr float C8[4] = {1.f, 0.70710678f, 0.f, -0.70710678f};
    constexpr float S8[4] = {0.f, 0.70710678f, 1.f, 0.70710678f};
#pragma unroll
    for (int g = 0; g < 16; g += 8)
#pragma unroll
        for (int j = 0; j < 4; ++j) bf(r[g+j], r[g+j+4], C8[j], D*S8[j]);
#pragma unroll
    for (int g = 0; g < 16; g += 4){
        bf(r[g],   r[g+2], 1.f, 0.f);
        bf(r[g+1], r[g+3], 0.f, D);
    }
#pragma unroll
    for (int g = 0; g < 16; g += 2) bf(r[g], r[g+1], 1.f, 0.f);
}

// Register twiddle: r[BREV(k1)] *= w^k1 with w = e^{DIR*2pi*i*t/256}.
// 1 sincos + 15 cmuls, no LDS table, no barrier. Recurrence rounding (~15 ulp)
// << fp32 FFT error (validated in p1 since r4).
template<int DIR>
__device__ __forceinline__ void twiddle_reg(vf2 r[16], int t){
    float sn, cn; __sincosf((float)DIR * 0.0245436926f * (float)t, &sn, &cn);
    vf2 w; w.x = cn; w.y = sn;
    vf2 wk = w;
#pragma unroll
    for (int k1 = 1; k1 < 16; ++k1){
        r[BREV(k1)] = cmul(r[BREV(k1)], wk);
        wk = cmul(wk, w);
    }
}

// Middle of four-step 256-pt FFT, t-SLOW layout (t = tid>>4): the 16x16
// transposes span waves -> 3 barriers (two-pass 8-line buffer; the old entry
// barrier is dropped -- every caller enters with sh8 untouched, and the
// write->read / read->overwrite hazards are covered by the 3 remaining ones).
// Register twiddles (no LDS tw table, no tw barrier).
// On entry r[n1] = x[16*n1 + t] for line l; on exit r[BREV(k2)] = X[t + 16*k2].
template<int DIR>
__device__ __forceinline__ void mid256r(vf2 r[16], vf2* sh8, int t, int l){
    fft16<DIR>(r);
    twiddle_reg<DIR>(r, t);
    int lr = l & 7;
    bool lo = (l < 8);
    if (lo){
#pragma unroll
        for (int k1 = 0; k1 < 16; ++k1) sh8[lr*LSTR + k1*16 + (t ^ k1)] = r[BREV(k1)];
    }
    __syncthreads();                      // W_lo before R_lo
    if (lo){
#pragma unroll
        for (int n2 = 0; n2 < 16; ++n2) r[n2] = sh8[lr*LSTR + t*16 + (n2 ^ t)];
    }
    __syncthreads();                      // R_lo before W_hi (same lines)
    if (!lo){
#pragma unroll
        for (int k1 = 0; k1 < 16; ++k1) sh8[lr*LSTR + k1*16 + (t ^ k1)] = r[BREV(k1)];
    }
    __syncthreads();                      // W_hi before R_hi
    if (!lo){
#pragma unroll
        for (int n2 = 0; n2 < 16; ++n2) r[n2] = sh8[lr*LSTR + t*16 + (n2 ^ t)];
    }
    fft16<DIR>(r);
}

// Intra-wave transpose core for the t-FAST layout (t = tid&15, l = tid>>4):
// each wave holds all 16 t for its 4 l-rows, so the 16x16 transposes are
// INTRA-WAVE. Lines l and l^2 time-share one LDS line in two phases; same-wave
// DS ops execute in issue order -> no s_barrier, but the phases must not be
// merged/reordered by the compiler: sched_barrier(0) fences them and phase B
// iterates in reverse so the bodies are not merge candidates.
__device__ __forceinline__ void wave_transpose(vf2 r[16], vf2* shw, int t, int l){
    vf2* base = shw + ((l >> 2)*2 + (l & 1))*LSTR;        // line shared by l and l^2
    if ((l & 2) == 0){                                    // phase A: l_local 0,1
#pragma unroll
        for (int k1 = 0; k1 < 16; ++k1) base[k1*16 + (t ^ k1)] = r[BREV(k1)];
#pragma unroll
        for (int n2 = 0; n2 < 16; ++n2) r[n2] = base[t*16 + (n2 ^ t)];
    }
    __builtin_amdgcn_sched_barrier(0);                    // A-reads issue before B-writes
    if ((l & 2) != 0){                                    // phase B: l_local 2,3 (reverse order)
#pragma unroll
        for (int k1 = 15; k1 >= 0; --k1) base[k1*16 + (t ^ k1)] = r[BREV(k1)];
#pragma unroll
        for (int n2 = 15; n2 >= 0; --n2) r[n2] = base[t*16 + (n2 ^ t)];
    }
}

// Barrier-free mid256 (t-fast) with register twiddles: ZERO __syncthreads.
template<int DIR>
__device__ __forceinline__ void mid256wr(vf2 r[16], vf2* shw, int t, int l){
    fft16<DIR>(r);
    twiddle_reg<DIR>(r, t);
    wave_transpose(r, shw, t, l);
    fft16<DIR>(r);
}

// Strided-axis FFT: 16 consecutive x per block, stride S elements.
// Reads only idx<NIN (rest structurally zero), writes only idx<NOUT.
// 3 barriers total (mid256r), no tw table.
template<int DIR, int NIN, int NOUT>
__device__ __forceinline__ void fft_strided(vf2* g, int S){
    __shared__ vf2 sh8[8*LSTR];
    int t = threadIdx.x >> 4, l = threadIdx.x & 15;
    vf2 r[16];
    vf2 zero; zero.x = 0.f; zero.y = 0.f;
#pragma unroll
    for (int n1 = 0; n1 < 16; ++n1)
        r[n1] = (n1 < NIN/16) ? g[(size_t)(16*n1 + t)*S + l] : zero;   // loads issue first
    mid256r<DIR>(r, sh8, t, l);
#pragma unroll
    for (int k2 = 0; k2 < 16; ++k2)
        if (k2 < NOUT/16) g[(size_t)(t + 16*k2)*S + l] = r[BREV(k2)];
}

// P1: read input, val = sqrt(relu(f*gz^2)), zero-pad 128->256, forward FFT along x
// with the half-pixel x-average folded ALGEBRAICALLY (same identity as p3y):
//   out[k] = FFT( x[n] * 0.5*(1 + e^{+2pi i n/256}) )[k]   (cyclic part)
//   out[128] = 0.5 * sum_n (-1)^n x[n]                      (dropped tap at k=128)
// t-FAST layout: direct coalesced global loads (no shin), intra-wave fix-up
// reduction (shfl_xor over t), barrier-free transpose + register twiddles
// (mid256wr), direct coalesced register->global stores. ZERO __syncthreads.
__global__ void __launch_bounds__(256) k_p1(const float* __restrict__ in, vf2* __restrict__ A){
    __shared__ vf2 sh8[8*LSTR];
    int tid = threadIdx.x, bid = blockIdx.x;         // v*1024 + z*8 + yc
    int yc = bid & 7, z = (bid >> 3) & 127, v = bid >> 10;
    int t = tid & 15, l = tid >> 4;                  // lanes 0..15 = consecutive x
    float gz = z * (1.0f/127.0f);
    float g2 = gz*gz;
    const float* src = in + (((size_t)(v*128 + z))*128 + yc*16 + l)*128;  // row y=yc*16+l
    float val[8];
#pragma unroll
    for (int n1 = 0; n1 < 8; ++n1) val[n1] = src[16*n1 + t];   // loads issue first
#pragma unroll
    for (int n1 = 0; n1 < 8; ++n1){
        float x = val[n1] * g2;
        val[n1] = x > 0.f ? sqrtf(x) : 0.f;
    }
    // k=128 fix-up: S = sum_n (-1)^n x[n]; n = 16*n1+t -> sign = (-1)^t. Intra-row
    // butterfly over t (t = low 4 bits of tid -> xor 1/2/4/8 stays in the row).
    float part = ((val[0]+val[1]) + (val[2]+val[3])) + ((val[4]+val[5]) + (val[6]+val[7]));
    part = (t & 1) ? -part : part;
    part += __shfl_xor(part, 1);
    part += __shfl_xor(part, 2);
    part += __shfl_xor(part, 4);
    part += __shfl_xor(part, 8);
    // prefilter (input real): r[n] = x[n] * 0.5*(1+cos, sin), theta = 2pi n/256
    vf2 r[16];
    vf2 zero; zero.x = 0.f; zero.y = 0.f;
#pragma unroll
    for (int n1 = 8; n1 < 16; ++n1) r[n1] = zero;
#pragma unroll
    for (int n1 = 0; n1 < 8; ++n1){
        float sn, cn; __sincosf(0.0245436926f * (float)(16*n1 + t), &sn, &cn);
        r[n1].x = val[n1] * 0.5f * (1.f + cn);
        r[n1].y = val[n1] * 0.5f * sn;
    }
    mid256wr<-1>(r, sh8, t, l);
    if (t == 0){ r[1].x = part*0.5f; r[1].y = 0.f; } // BREV(8)=1 -> X[128], real
    vf2* dst = A + (size_t)v*VS + (size_t)z*ZSTR + (size_t)(yc*16 + l)*YSTR;
#pragma unroll
    for (int k2 = 0; k2 < 16; ++k2)                  // x = t+16*k2, 16 lanes = 128B
        dst[t + 16*k2] = r[BREV(k2)];
}

// P2z: forward FFT along z — runs BEFORE the y-FFT so only y<128 columns exist:
// half the traffic of the old ordering. Read z<128, write z<128. In-place.
__global__ void __launch_bounds__(256) k_p2z(vf2* __restrict__ A){
    int bid = blockIdx.x;                            // v*2048 + y*16 + xb   (y < 128)
    int xb = bid & 15, y = (bid >> 4) & 127, v = bid >> 11;
    fft_strided<-1,128,128>(A + (size_t)v*VS + (size_t)y*YSTR + xb*16, ZSTR);
}

// P3y: forward FFT along y for each z<128 slab (read y<128, write 256).
// The half-pixel y-average is folded in ALGEBRAICALLY:
//   out[k] = 0.5*(X[k] + X[k-1 mod 256])            (cyclic part)
//          = FFT( x[n] * 0.5*(1 + e^{+2pi i n/256}) )   -- pre-multiply on input
//   out[128] = 0.5*X[128] = 0.5*sum_n (-1)^n x[n]    (prev tap dropped at k=128)
// 3 barriers (mid256r); shW ordering covered by mid256r's internal barriers.
__global__ void __launch_bounds__(256) k_p3y(vf2* __restrict__ A){
    __shared__ vf2 sh8[8*LSTR];
    __shared__ vf2 shW[64];                          // per-wave partials of sum (-1)^n x[n]
    int bid = blockIdx.x;                            // v*2048 + z*16 + xb   (z < 128)
    int xb = bid & 15, z = (bid >> 4) & 127, v = bid >> 11;
    vf2* g = A + (size_t)v*VS + (size_t)z*ZSTR + xb*16;
    int t = threadIdx.x >> 4, l = threadIdx.x & 15;
    vf2 r[16];
    vf2 zero; zero.x = 0.f; zero.y = 0.f;
#pragma unroll
    for (int n1 = 0; n1 < 16; ++n1)
        r[n1] = (n1 < 8) ? g[(size_t)(16*n1 + t)*YSTR + l] : zero;   // loads issue first

    // alternating-sum partial from RAW inputs: sum over this thread's n = 16*n1+t
    // (-1)^n = (-1)^t since 16*n1 is even.
    vf2 part = ((r[0]+r[1]) + (r[2]+r[3])) + ((r[4]+r[5]) + (r[6]+r[7]));
    part = part * ((t & 1) ? -1.f : 1.f);
    part.x += __shfl_xor(part.x, 16);                // t ^ 1  (within wave)
    part.y += __shfl_xor(part.y, 16);
    part.x += __shfl_xor(part.x, 32);                // t ^ 2  (within wave)
    part.y += __shfl_xor(part.y, 32);
    if ((t & 3) == 0) shW[(t >> 2)*16 + l] = part;   // one entry per (wave, l)

    // cyclic-average pre-filter: r[n] *= 0.5*(1 + e^{+2pi i n/256})
#pragma unroll
    for (int n1 = 0; n1 < 8; ++n1){
        float sn, cn; __sincosf(0.0245436926f * (float)(16*n1 + t), &sn, &cn);
        vf2 c; c.x = 0.5f*(1.f + cn); c.y = 0.5f*sn;
        r[n1] = cmul(r[n1], c);
    }

    mid256r<-1>(r, sh8, t, l);                       // internal barriers order shW too

    if (t == 0){                                     // k = 128 fix-up (t=0, k2=8)
        vf2 S = (shW[l] + shW[16 + l]) + (shW[32 + l] + shW[48 + l]);
        r[BREV(8)] = S * 0.5f;
    }
#pragma unroll
    for (int k2 = 0; k2 < 16; ++k2)                  // direct store: 16 x-lanes = 128B
        g[(size_t)(t + 16*k2)*YSTR + l] = r[BREV(k2)];
}

// P45: fused Stolt z-resample (2 taps — x/y averaging baked into A) + x-iFFT.
// Direct global->register gather (roles t=tid&15 lane-fast for coalescing) and
// direct register->global store — no staging LDS, full load MLP.
// t-fast layout + register twiddles -> ZERO barriers: waves fully independent.
__global__ void __launch_bounds__(256) k_p45(const vf2* __restrict__ A, vf2* __restrict__ B){
    __shared__ vf2 sh8[8*LSTR];
    int tid = threadIdx.x, bid = blockIdx.x;         // v*2048 + zn*16 + yc
    int yc = bid & 15, zn = (bid >> 4) & 127, v = bid >> 11;
    const vf2* Av = A + (size_t)v*VS;
    int t = tid & 15, l = tid >> 4;                  // lanes 0..15 = consecutive x
    int yn = yc*16 + l;
    float gy = (yn < 128 ? yn : yn - 256) * (1.0f/128.0f);
    float gz = zn * (1.0f/128.0f);
    float c2 = 0.1024f*gy*gy + gz*gz;
    unsigned rowoff = (unsigned)yn*YSTR;
    vf2 r[16];
#pragma unroll
    for (int n1 = 0; n1 < 16; ++n1){
        int xn = 16*n1 + t;
        float gx = (xn < 128 ? xn : xn - 256) * (1.0f/128.0f);
        float s2 = c2 + 0.1024f*gx*gx;
        float rs = __builtin_amdgcn_rsqf(s2 + 1e-12f);   // 1/gznew; zn==0 row -> wf=0
        float gznew = s2 * rs;
        float pz = gznew*128.0f + 127.5f;
        int zi = (int)pz;                                // trunc == floor (pz>0)
        float dz = pz - (float)zi;
        int zp0 = zi - 128;                              // natural z of first tap
        float wf = gz * rs;                              // gz/gznew
        float w0 = (((unsigned)zp0     < 128u) ? (1.0f - dz) : 0.f) * wf;
        float w1 = (((unsigned)(zp0+1) < 128u) ? dz : 0.f) * wf;
        vf2 v0 = Av[(size_t)((unsigned)(zp0 & 127) * ZSTR) + rowoff + xn];
        vf2 v1 = Av[(size_t)((unsigned)((zp0 + 1) & 127) * ZSTR) + rowoff + xn];
        r[n1] = v0*w0 + v1*w1;
    }
    mid256wr<1>(r, sh8, t, l);
    vf2* dst = B + (size_t)v*VSB + (size_t)zn*BZS + (size_t)yn*BYS;
#pragma unroll
    for (int k2 = 0; k2 < 8; ++k2)                   // x = t+16*k2 < 128, coalesced
        dst[t + 16*k2] = r[BREV(k2)];
}

// P6: inverse FFT along y on packed B (x<128). Read all 256 y, write y<128. In-place.
__global__ void __launch_bounds__(256) k_p6(vf2* __restrict__ B){
    int bid = blockIdx.x;                            // v*1024 + zn*8 + xb
    int xb = bid & 7, zn = (bid >> 3) & 127, v = bid >> 10;
    fft_strided<1,256,128>(B + (size_t)v*VSB + (size_t)zn*BZS + xb*16, BYS);
}

// P7: inverse FFT along z for y<128, x<128 on packed B. Read zn<128,
// output real part of z<128 scaled by 1/256^3 into d_out.
__global__ void __launch_bounds__(256) k_p7(const vf2* __restrict__ B, float* __restrict__ out){
    __shared__ vf2 sh8[8*LSTR];
    int bid = blockIdx.x;                            // v*1024 + y*8 + xb
    int xb = bid & 7, y = (bid >> 3) & 127, v = bid >> 10;
    const vf2* g = B + (size_t)v*VSB + (size_t)y*BYS + xb*16;
    int t = threadIdx.x >> 4, l = threadIdx.x & 15;
    vf2 r[16];
    vf2 zero; zero.x = 0.f; zero.y = 0.f;
#pragma unroll
    for (int n1 = 0; n1 < 16; ++n1)
        r[n1] = (n1 < 8) ? g[(size_t)(16*n1 + t)*BZS + l] : zero;
    mid256r<1>(r, sh8, t, l);
    const float sc = 1.0f/16777216.0f;               // 1/256^3
    float* dst = out + ((size_t)(v*128)*128 + y)*128 + xb*16 + l;
#pragma unroll
    for (int k2 = 0; k2 < 8; ++k2)                   // k = t + 16*k2 < 128
        dst[(size_t)(t + 16*k2)*16384] = r[BREV(k2)].x * sc;
}

extern "C" void kernel_launch(void* const* d_in, const int* in_sizes, int n_in,
                              void* d_out, int out_size, void* d_ws, size_t ws_size,
                              hipStream_t stream){
    const float* in = (const float*)d_in[0];
    float* out = (float*)d_out;
    vf2* A = (vf2*)d_ws;                   // 134 MB
    vf2* B = A + 2*VS;                     // 67 MB packed
    k_p1 <<< 2048, 256, 0, stream>>>(in, A);
    k_p2z<<< 4096, 256, 0, stream>>>(A);   // z-FFT first: y<128 -> half traffic
    k_p3y<<< 4096, 256, 0, stream>>>(A);
    k_p45<<< 4096, 256, 0, stream>>>(A, B);
    k_p6 <<< 2048, 256, 0, stream>>>(B);
    k_p7 <<< 2048, 256, 0, stream>>>(B, out);
}

// Round 6
// 196.230 us; speedup vs baseline: 1.0255x; 1.0255x over previous
//
#include <hip/hip_runtime.h>

// Geometry: M=N=128, padded S=256. Two volumes (b*d=2).
// A: [v][z<128][y:256][x:256] complex fp32 = 134 MB total.
// B (packed): [v][z<128][y:256][x<128] complex fp32 = 67 MB total.
// Forward pass order: x-FFT -> z-FFT (y still <128: half traffic) -> y-FFT.
static constexpr size_t VS   = 8388608;  // 128*256*256 per volume (A)
static constexpr int    ZSTR = 65536;    // 256*256
static constexpr int    YSTR = 256;
static constexpr size_t VSB  = 4194304;  // 128*256*128 per volume (B)
static constexpr int    BZS  = 32768;    // 256*128
static constexpr int    BYS  = 128;
static constexpr int    LSTR = 261;      // LDS line stride (vf2); 5*l mod 16 spreads bank-pairs

typedef float vf2 __attribute__((ext_vector_type(2)));  // complex: .x=re, .y=im -> v_pk_* f32

__device__ __forceinline__ vf2 cmul(vf2 a, vf2 b){
    vf2 asw; asw.x = -a.y; asw.y = a.x;       // i*a
    return a*b.x + asw*b.y;                   // pk_mul + pk_fma
}

constexpr int BREV(int k){ return ((k&1)<<3)|((k&2)<<1)|((k&4)>>1)|((k&8)>>3); }

// Butterfly: a' = a+b; b' = (a-b) rotated by (c,s). Packed VOP3P.
__device__ __forceinline__ void bf(vf2& a, vf2& b, float c, float s){
    vf2 sum = a + b;
    vf2 dif = a - b;
    vf2 dsw; dsw.x = -dif.y; dsw.y = dif.x;   // i*dif
    b = dif*c + dsw*s;
    a = sum;
}

// Fully-unrolled 16-pt DIF FFT, natural input, bit-reversed output: X[k] = r[BREV(k)].
template<int DIR>
__device__ __forceinline__ void fft16(vf2 r[16]){
    constexpr float D = (float)DIR;
    constexpr float C16[8] = {1.f, 0.92387953f, 0.70710678f, 0.38268343f, 0.f, -0.38268343f, -0.70710678f, -0.92387953f};
    constexpr float S16[8] = {0.f, 0.38268343f, 0.70710678f, 0.92387953f, 1.f, 0.92387953f, 0.70710678f, 0.38268343f};
#pragma unroll
    for (int j = 0; j < 8; ++j) bf(r[j], r[j+8], C16[j], D*S16[j]);
    constexpr float C8[4] = {1.f, 0.70710678f, 0.f, -0.70710678f};
    constexpr float S8[4] = {0.f, 0.70710678f, 1.f, 0.70710678f};
#pragma unroll
    for (int g = 0; g < 16; g += 8)
#pragma unroll
        for (int j = 0; j < 4; ++j) bf(r[g+j], r[g+j+4], C8[j], D*S8[j]);
#pragma unroll
    for (int g = 0; g < 16; g += 4){
        bf(r[g],   r[g+2], 1.f, 0.f);
        bf(r[g+1], r[g+3], 0.f, D);
    }
#pragma unroll
    for (int g = 0; g < 16; g += 2) bf(r[g], r[g+1], 1.f, 0.f);
}

// Per-block twiddle table: tw[a*16+b] = e^{DIR*2pi*i*a*b/256}.
// Caller must barrier between init and first use. (Table beats a register
// recurrence: the recurrence is a serial 15-cmul dependency chain -- measured
// regression in r5 on the t-slow kernels.)
__device__ __forceinline__ void init_tw(vf2* tw, float dir){
    int tid = threadIdx.x;
    float ang = dir * 0.0245436926f * (float)((tid >> 4)*(tid & 15));
    float s, c; __sincosf(ang, &s, &c);
    vf2 w; w.x = c; w.y = s;
    tw[tid] = w;
}

// Middle of four-step 256-pt FFT, t-SLOW layout (t = tid>>4): the 16x16
// transposes span waves. Two-pass 8-line buffer; 3 internal barriers (the old
// entry barrier is dropped -- every caller enters with sh8 untouched and the
// caller's tw barrier already rendezvoused all threads after the loads).
// On entry r[n1] = x[16*n1 + t] for line l; on exit r[BREV(k2)] = X[t + 16*k2].
template<int DIR>
__device__ __forceinline__ void mid256t(vf2 r[16], vf2* sh8, const vf2* tw, int t, int l){
    fft16<DIR>(r);
#pragma unroll
    for (int k1 = 1; k1 < 16; ++k1)
        r[BREV(k1)] = cmul(r[BREV(k1)], tw[k1*16 + t]);   // broadcast across l
    int lr = l & 7;
    bool lo = (l < 8);
    if (lo){
#pragma unroll
        for (int k1 = 0; k1 < 16; ++k1) sh8[lr*LSTR + k1*16 + (t ^ k1)] = r[BREV(k1)];
    }
    __syncthreads();                      // W_lo before R_lo
    if (lo){
#pragma unroll
        for (int n2 = 0; n2 < 16; ++n2) r[n2] = sh8[lr*LSTR + t*16 + (n2 ^ t)];
    }
    __syncthreads();                      // R_lo before W_hi (same lines)
    if (!lo){
#pragma unroll
        for (int k1 = 0; k1 < 16; ++k1) sh8[lr*LSTR + k1*16 + (t ^ k1)] = r[BREV(k1)];
    }
    __syncthreads();                      // W_hi before R_hi
    if (!lo){
#pragma unroll
        for (int n2 = 0; n2 < 16; ++n2) r[n2] = sh8[lr*LSTR + t*16 + (n2 ^ t)];
    }
    fft16<DIR>(r);
}

// Register twiddle for the BARRIER-FREE t-fast path only (p1/p45, where gather
// latency hides the serial chain): r[BREV(k1)] *= w^k1, w = e^{DIR*2pi*i*t/256}.
template<int DIR>
__device__ __forceinline__ void twiddle_reg(vf2 r[16], int t){
    float sn, cn; __sincosf((float)DIR * 0.0245436926f * (float)t, &sn, &cn);
    vf2 w; w.x = cn; w.y = sn;
    vf2 wk = w;
#pragma unroll
    for (int k1 = 1; k1 < 16; ++k1){
        r[BREV(k1)] = cmul(r[BREV(k1)], wk);
        wk = cmul(wk, w);
    }
}

// Intra-wave transpose core for the t-FAST layout (t = tid&15, l = tid>>4):
// each wave holds all 16 t for its 4 l-rows, so the 16x16 transposes are
// INTRA-WAVE. Lines l and l^2 time-share one LDS line in two phases; same-wave
// DS ops execute in issue order -> no s_barrier, but the phases must not be
// merged/reordered by the compiler: sched_barrier(0) fences them and phase B
// iterates in reverse so the bodies are not merge candidates.
__device__ __forceinline__ void wave_transpose(vf2 r[16], vf2* shw, int t, int l){
    vf2* base = shw + ((l >> 2)*2 + (l & 1))*LSTR;        // line shared by l and l^2
    if ((l & 2) == 0){                                    // phase A: l_local 0,1
#pragma unroll
        for (int k1 = 0; k1 < 16; ++k1) base[k1*16 + (t ^ k1)] = r[BREV(k1)];
#pragma unroll
        for (int n2 = 0; n2 < 16; ++n2) r[n2] = base[t*16 + (n2 ^ t)];
    }
    __builtin_amdgcn_sched_barrier(0);                    // A-reads issue before B-writes
    if ((l & 2) != 0){                                    // phase B: l_local 2,3 (reverse order)
#pragma unroll
        for (int k1 = 15; k1 >= 0; --k1) base[k1*16 + (t ^ k1)] = r[BREV(k1)];
#pragma unroll
        for (int n2 = 15; n2 >= 0; --n2) r[n2] = base[t*16 + (n2 ^ t)];
    }
}

// Barrier-free mid256 (t-fast) with register twiddles: ZERO __syncthreads.
template<int DIR>
__device__ __forceinline__ void mid256wr(vf2 r[16], vf2* shw, int t, int l){
    fft16<DIR>(r);
    twiddle_reg<DIR>(r, t);
    wave_transpose(r, shw, t, l);
    fft16<DIR>(r);
}

// Strided-axis FFT: 16 consecutive x per block, stride S elements.
// Reads only idx<NIN (rest structurally zero), writes only idx<NOUT.
// 4 barriers total (1 tw + 3 in mid256t).
template<int DIR, int NIN, int NOUT>
__device__ __forceinline__ void fft_strided(vf2* g, int S){
    __shared__ vf2 sh8[8*LSTR];
    __shared__ vf2 tw[256];
    int t = threadIdx.x >> 4, l = threadIdx.x & 15;
    vf2 r[16];
    vf2 zero; zero.x = 0.f; zero.y = 0.f;
#pragma unroll
    for (int n1 = 0; n1 < 16; ++n1)
        r[n1] = (n1 < NIN/16) ? g[(size_t)(16*n1 + t)*S + l] : zero;   // loads issue first
    init_tw(tw, (float)DIR);
    __syncthreads();                                 // tw ready
    mid256t<DIR>(r, sh8, tw, t, l);
#pragma unroll
    for (int k2 = 0; k2 < 16; ++k2)
        if (k2 < NOUT/16) g[(size_t)(t + 16*k2)*S + l] = r[BREV(k2)];
}

// P1: read input, val = sqrt(relu(f*gz^2)), zero-pad 128->256, forward FFT along x
// with the half-pixel x-average folded ALGEBRAICALLY (same identity as p3y):
//   out[k] = FFT( x[n] * 0.5*(1 + e^{+2pi i n/256}) )[k]   (cyclic part)
//   out[128] = 0.5 * sum_n (-1)^n x[n]                      (dropped tap at k=128)
// t-FAST layout: direct coalesced global loads (no shin), intra-wave fix-up
// reduction (shfl_xor over t), barrier-free transpose + register twiddles
// (mid256wr), direct coalesced register->global stores. ZERO __syncthreads.
__global__ void __launch_bounds__(256) k_p1(const float* __restrict__ in, vf2* __restrict__ A){
    __shared__ vf2 sh8[8*LSTR];
    int tid = threadIdx.x, bid = blockIdx.x;         // v*1024 + z*8 + yc
    int yc = bid & 7, z = (bid >> 3) & 127, v = bid >> 10;
    int t = tid & 15, l = tid >> 4;                  // lanes 0..15 = consecutive x
    float gz = z * (1.0f/127.0f);
    float g2 = gz*gz;
    const float* src = in + (((size_t)(v*128 + z))*128 + yc*16 + l)*128;  // row y=yc*16+l
    float val[8];
#pragma unroll
    for (int n1 = 0; n1 < 8; ++n1) val[n1] = src[16*n1 + t];   // loads issue first
#pragma unroll
    for (int n1 = 0; n1 < 8; ++n1){
        float x = val[n1] * g2;
        val[n1] = x > 0.f ? sqrtf(x) : 0.f;
    }
    // k=128 fix-up: S = sum_n (-1)^n x[n]; n = 16*n1+t -> sign = (-1)^t. Intra-row
    // butterfly over t (t = low 4 bits of tid -> xor 1/2/4/8 stays in the row).
    float part = ((val[0]+val[1]) + (val[2]+val[3])) + ((val[4]+val[5]) + (val[6]+val[7]));
    part = (t & 1) ? -part : part;
    part += __shfl_xor(part, 1);
    part += __shfl_xor(part, 2);
    part += __shfl_xor(part, 4);
    part += __shfl_xor(part, 8);
    // prefilter (input real): r[n] = x[n] * 0.5*(1+cos, sin), theta = 2pi n/256
    vf2 r[16];
    vf2 zero; zero.x = 0.f; zero.y = 0.f;
#pragma unroll
    for (int n1 = 8; n1 < 16; ++n1) r[n1] = zero;
#pragma unroll
    for (int n1 = 0; n1 < 8; ++n1){
        float sn, cn; __sincosf(0.0245436926f * (float)(16*n1 + t), &sn, &cn);
        r[n1].x = val[n1] * 0.5f * (1.f + cn);
        r[n1].y = val[n1] * 0.5f * sn;
    }
    mid256wr<-1>(r, sh8, t, l);
    if (t == 0){ r[1].x = part*0.5f; r[1].y = 0.f; } // BREV(8)=1 -> X[128], real
    vf2* dst = A + (size_t)v*VS + (size_t)z*ZSTR + (size_t)(yc*16 + l)*YSTR;
#pragma unroll
    for (int k2 = 0; k2 < 16; ++k2)                  // x = t+16*k2, 16 lanes = 128B
        dst[t + 16*k2] = r[BREV(k2)];
}

// P2z: forward FFT along z — runs BEFORE the y-FFT so only y<128 columns exist:
// half the traffic of the old ordering. Read z<128, write z<128. In-place.
__global__ void __launch_bounds__(256) k_p2z(vf2* __restrict__ A){
    int bid = blockIdx.x;                            // v*2048 + y*16 + xb   (y < 128)
    int xb = bid & 15, y = (bid >> 4) & 127, v = bid >> 11;
    fft_strided<-1,128,128>(A + (size_t)v*VS + (size_t)y*YSTR + xb*16, ZSTR);
}

// P3y: forward FFT along y for each z<128 slab (read y<128, write 256).
// The half-pixel y-average is folded in ALGEBRAICALLY:
//   out[k] = 0.5*(X[k] + X[k-1 mod 256])            (cyclic part)
//          = FFT( x[n] * 0.5*(1 + e^{+2pi i n/256}) )   -- pre-multiply on input
//   out[128] = 0.5*X[128] = 0.5*sum_n (-1)^n x[n]    (prev tap dropped at k=128)
// 4 barriers (tw + mid256t); shW ordering covered by the same barriers.
__global__ void __launch_bounds__(256) k_p3y(vf2* __restrict__ A){
    __shared__ vf2 sh8[8*LSTR];
    __shared__ vf2 tw[256];
    __shared__ vf2 shW[64];                          // per-wave partials of sum (-1)^n x[n]
    int bid = blockIdx.x;                            // v*2048 + z*16 + xb   (z < 128)
    int xb = bid & 15, z = (bid >> 4) & 127, v = bid >> 11;
    vf2* g = A + (size_t)v*VS + (size_t)z*ZSTR + xb*16;
    int t = threadIdx.x >> 4, l = threadIdx.x & 15;
    vf2 r[16];
    vf2 zero; zero.x = 0.f; zero.y = 0.f;
#pragma unroll
    for (int n1 = 0; n1 < 16; ++n1)
        r[n1] = (n1 < 8) ? g[(size_t)(16*n1 + t)*YSTR + l] : zero;   // loads issue first

    // alternating-sum partial from RAW inputs: sum over this thread's n = 16*n1+t
    // (-1)^n = (-1)^t since 16*n1 is even.
    vf2 part = ((r[0]+r[1]) + (r[2]+r[3])) + ((r[4]+r[5]) + (r[6]+r[7]));
    part = part * ((t & 1) ? -1.f : 1.f);
    part.x += __shfl_xor(part.x, 16);                // t ^ 1  (within wave)
    part.y += __shfl_xor(part.y, 16);
    part.x += __shfl_xor(part.x, 32);                // t ^ 2  (within wave)
    part.y += __shfl_xor(part.y, 32);
    if ((t & 3) == 0) shW[(t >> 2)*16 + l] = part;   // one entry per (wave, l)

    // cyclic-average pre-filter: r[n] *= 0.5*(1 + e^{+2pi i n/256})
#pragma unroll
    for (int n1 = 0; n1 < 8; ++n1){
        float sn, cn; __sincosf(0.0245436926f * (float)(16*n1 + t), &sn, &cn);
        vf2 c; c.x = 0.5f*(1.f + cn); c.y = 0.5f*sn;
        r[n1] = cmul(r[n1], c);
    }

    init_tw(tw, -1.f);
    __syncthreads();                                 // tw + shW ready
    mid256t<-1>(r, sh8, tw, t, l);

    if (t == 0){                                     // k = 128 fix-up (t=0, k2=8)
        vf2 S = (shW[l] + shW[16 + l]) + (shW[32 + l] + shW[48 + l]);
        r[BREV(8)] = S * 0.5f;
    }
#pragma unroll
    for (int k2 = 0; k2 < 16; ++k2)                  // direct store: 16 x-lanes = 128B
        g[(size_t)(t + 16*k2)*YSTR + l] = r[BREV(k2)];
}

// P45: fused Stolt z-resample (2 taps — x/y averaging baked into A) + x-iFFT.
// Direct global->register gather (roles t=tid&15 lane-fast for coalescing) and
// direct register->global store — no staging LDS, full load MLP.
// t-fast layout + register twiddles -> ZERO barriers: waves fully independent.
// NOTE (r5): p45 is gather-bandwidth-bound (~268 MB reads, L3-served, ~7 TB/s
// aggregate) -- barrier/twiddle variants are noise-neutral here.
__global__ void __launch_bounds__(256) k_p45(const vf2* __restrict__ A, vf2* __restrict__ B){
    __shared__ vf2 sh8[8*LSTR];
    int tid = threadIdx.x, bid = blockIdx.x;         // v*2048 + zn*16 + yc
    int yc = bid & 15, zn = (bid >> 4) & 127, v = bid >> 11;
    const vf2* Av = A + (size_t)v*VS;
    int t = tid & 15, l = tid >> 4;                  // lanes 0..15 = consecutive x
    int yn = yc*16 + l;
    float gy = (yn < 128 ? yn : yn - 256) * (1.0f/128.0f);
    float gz = zn * (1.0f/128.0f);
    float c2 = 0.1024f*gy*gy + gz*gz;
    unsigned rowoff = (unsigned)yn*YSTR;
    vf2 r[16];
#pragma unroll
    for (int n1 = 0; n1 < 16; ++n1){
        int xn = 16*n1 + t;
        float gx = (xn < 128 ? xn : xn - 256) * (1.0f/128.0f);
        float s2 = c2 + 0.1024f*gx*gx;
        float rs = __builtin_amdgcn_rsqf(s2 + 1e-12f);   // 1/gznew; zn==0 row -> wf=0
        float gznew = s2 * rs;
        float pz = gznew*128.0f + 127.5f;
        int zi = (int)pz;                                // trunc == floor (pz>0)
        float dz = pz - (float)zi;
        int zp0 = zi - 128;                              // natural z of first tap
        float wf = gz * rs;                              // gz/gznew
        float w0 = (((unsigned)zp0     < 128u) ? (1.0f - dz) : 0.f) * wf;
        float w1 = (((unsigned)(zp0+1) < 128u) ? dz : 0.f) * wf;
        vf2 v0 = Av[(size_t)((unsigned)(zp0 & 127) * ZSTR) + rowoff + xn];
        vf2 v1 = Av[(size_t)((unsigned)((zp0 + 1) & 127) * ZSTR) + rowoff + xn];
        r[n1] = v0*w0 + v1*w1;
    }
    mid256wr<1>(r, sh8, t, l);
    vf2* dst = B + (size_t)v*VSB + (size_t)zn*BZS + (size_t)yn*BYS;
#pragma unroll
    for (int k2 = 0; k2 < 8; ++k2)                   // x = t+16*k2 < 128, coalesced
        dst[t + 16*k2] = r[BREV(k2)];
}

// P6: inverse FFT along y on packed B (x<128). Read all 256 y, write y<128. In-place.
__global__ void __launch_bounds__(256) k_p6(vf2* __restrict__ B){
    int bid = blockIdx.x;                            // v*1024 + zn*8 + xb
    int xb = bid & 7, zn = (bid >> 3) & 127, v = bid >> 10;
    fft_strided<1,256,128>(B + (size_t)v*VSB + (size_t)zn*BZS + xb*16, BYS);
}

// P7: inverse FFT along z for y<128, x<128 on packed B. Read zn<128,
// output real part of z<128 scaled by 1/256^3 into d_out.
__global__ void __launch_bounds__(256) k_p7(const vf2* __restrict__ B, float* __restrict__ out){
    __shared__ vf2 sh8[8*LSTR];
    __shared__ vf2 tw[256];
    int bid = blockIdx.x;                            // v*1024 + y*8 + xb
    int xb = bid & 7, y = (bid >> 3) & 127, v = bid >> 10;
    const vf2* g = B + (size_t)v*VSB + (size_t)y*BYS + xb*16;
    int t = threadIdx.x >> 4, l = threadIdx.x & 15;
    vf2 r[16];
    vf2 zero; zero.x = 0.f; zero.y = 0.f;
#pragma unroll
    for (int n1 = 0; n1 < 16; ++n1)
        r[n1] = (n1 < 8) ? g[(size_t)(16*n1 + t)*BZS + l] : zero;
    init_tw(tw, 1.f);
    __syncthreads();
    mid256t<1>(r, sh8, tw, t, l);
    const float sc = 1.0f/16777216.0f;               // 1/256^3
    float* dst = out + ((size_t)(v*128)*128 + y)*128 + xb*16 + l;
#pragma unroll
    for (int k2 = 0; k2 < 8; ++k2)                   // k = t + 16*k2 < 128
        dst[(size_t)(t + 16*k2)*16384] = r[BREV(k2)].x * sc;
}

extern "C" void kernel_launch(void* const* d_in, const int* in_sizes, int n_in,
                              void* d_out, int out_size, void* d_ws, size_t ws_size,
                              hipStream_t stream){
    const float* in = (const float*)d_in[0];
    float* out = (float*)d_out;
    vf2* A = (vf2*)d_ws;                   // 134 MB
    vf2* B = A + 2*VS;                     // 67 MB packed
    k_p1 <<< 2048, 256, 0, stream>>>(in, A);
    k_p2z<<< 4096, 256, 0, stream>>>(A);   // z-FFT first: y<128 -> half traffic
    k_p3y<<< 4096, 256, 0, stream>>>(A);
    k_p45<<< 4096, 256, 0, stream>>>(A, B);
    k_p6 <<< 2048, 256, 0, stream>>>(B);
    k_p7 <<< 2048, 256, 0, stream>>>(B, out);
}

// Round 7
// 184.961 us; speedup vs baseline: 1.0880x; 1.0609x over previous
//
#include <hip/hip_runtime.h>

// Geometry: M=N=128, padded S=256. Two volumes (b*d=2).
// A: [v][z<128][y:256][x:256] complex FP16-PACKED (uint32 = re:f16 | im:f16<<16) = 67 MB.
// B (packed): [v][z<128][y:256][x<128] complex fp16 = 33.5 MB.
// Per-stage folded scales keep fp16 in range (worst-case stage maxima in ()):
//   p1 x1 (<=128) -> p2z x1 (<=16384) -> p3y x2^-6 (<=32768) -> p45 x1 (w<=1)
//   -> p6 x2^-8 (<=32768) -> p7 x2^-10  == old 1/256^3 total.
static constexpr size_t VS   = 8388608;  // 128*256*256 per volume (A), elements
static constexpr int    ZSTR = 65536;    // 256*256
static constexpr int    YSTR = 256;
static constexpr size_t VSB  = 4194304;  // 128*256*128 per volume (B), elements
static constexpr int    BZS  = 32768;    // 256*128
static constexpr int    BYS  = 128;
static constexpr int    LSTR = 261;      // LDS line stride (vf2); 5*l mod 16 spreads bank-pairs

typedef float vf2 __attribute__((ext_vector_type(2)));       // complex fp32 in regs
typedef _Float16 h2 __attribute__((ext_vector_type(2)));     // packed fp16 pair

// fp16 pack/unpack (v_cvt_f16_f32 RNE / v_cvt_f32_f16)
__device__ __forceinline__ unsigned pkh(vf2 a){
    h2 h; h.x = (_Float16)a.x; h.y = (_Float16)a.y;
    return __builtin_bit_cast(unsigned, h);
}
__device__ __forceinline__ vf2 uph(unsigned u){
    h2 h = __builtin_bit_cast(h2, u);
    vf2 r; r.x = (float)h.x; r.y = (float)h.y; return r;
}

__device__ __forceinline__ vf2 cmul(vf2 a, vf2 b){
    vf2 asw; asw.x = -a.y; asw.y = a.x;       // i*a
    return a*b.x + asw*b.y;                   // pk_mul + pk_fma
}

constexpr int BREV(int k){ return ((k&1)<<3)|((k&2)<<1)|((k&4)>>1)|((k&8)>>3); }

// Butterfly: a' = a+b; b' = (a-b) rotated by (c,s). Packed VOP3P.
__device__ __forceinline__ void bf(vf2& a, vf2& b, float c, float s){
    vf2 sum = a + b;
    vf2 dif = a - b;
    vf2 dsw; dsw.x = -dif.y; dsw.y = dif.x;   // i*dif
    b = dif*c + dsw*s;
    a = sum;
}

// Fully-unrolled 16-pt DIF FFT, natural input, bit-reversed output: X[k] = r[BREV(k)].
template<int DIR>
__device__ __forceinline__ void fft16(vf2 r[16]){
    constexpr float D = (float)DIR;
    constexpr float C16[8] = {1.f, 0.92387953f, 0.70710678f, 0.38268343f, 0.f, -0.38268343f, -0.70710678f, -0.92387953f};
    constexpr float S16[8] = {0.f, 0.38268343f, 0.70710678f, 0.92387953f, 1.f, 0.92387953f, 0.70710678f, 0.38268343f};
#pragma unroll
    for (int j = 0; j < 8; ++j) bf(r[j], r[j+8], C16[j], D*S16[j]);
    constexpr float C8[4] = {1.f, 0.70710678f, 0.f, -0.70710678f};
    constexpr float S8[4] = {0.f, 0.70710678f, 1.f, 0.70710678f};
#pragma unroll
    for (int g = 0; g < 16; g += 8)
#pragma unroll
        for (int j = 0; j < 4; ++j) bf(r[g+j], r[g+j+4], C8[j], D*S8[j]);
#pragma unroll
    for (int g = 0; g < 16; g += 4){
        bf(r[g],   r[g+2], 1.f, 0.f);
        bf(r[g+1], r[g+3], 0.f, D);
    }
#pragma unroll
    for (int g = 0; g < 16; g += 2) bf(r[g], r[g+1], 1.f, 0.f);
}

// Per-block twiddle table: tw[a*16+b] = e^{DIR*2pi*i*a*b/256}.
// Caller must barrier between init and first use. (Table beats a register
// recurrence on t-slow kernels: serial 15-cmul chain regressed in r5.)
__device__ __forceinline__ void init_tw(vf2* tw, float dir){
    int tid = threadIdx.x;
    float ang = dir * 0.0245436926f * (float)((tid >> 4)*(tid & 15));
    float s, c; __sincosf(ang, &s, &c);
    vf2 w; w.x = c; w.y = s;
    tw[tid] = w;
}

// Middle of four-step 256-pt FFT, t-SLOW layout (t = tid>>4): transposes span
// waves. Two-pass 8-line buffer; 3 internal barriers (entry barrier dropped --
// callers enter with sh8 untouched and the tw barrier already rendezvoused).
// On entry r[n1] = x[16*n1 + t] for line l; on exit r[BREV(k2)] = X[t + 16*k2].
template<int DIR>
__device__ __forceinline__ void mid256t(vf2 r[16], vf2* sh8, const vf2* tw, int t, int l){
    fft16<DIR>(r);
#pragma unroll
    for (int k1 = 1; k1 < 16; ++k1)
        r[BREV(k1)] = cmul(r[BREV(k1)], tw[k1*16 + t]);   // broadcast across l
    int lr = l & 7;
    bool lo = (l < 8);
    if (lo){
#pragma unroll
        for (int k1 = 0; k1 < 16; ++k1) sh8[lr*LSTR + k1*16 + (t ^ k1)] = r[BREV(k1)];
    }
    __syncthreads();                      // W_lo before R_lo
    if (lo){
#pragma unroll
        for (int n2 = 0; n2 < 16; ++n2) r[n2] = sh8[lr*LSTR + t*16 + (n2 ^ t)];
    }
    __syncthreads();                      // R_lo before W_hi (same lines)
    if (!lo){
#pragma unroll
        for (int k1 = 0; k1 < 16; ++k1) sh8[lr*LSTR + k1*16 + (t ^ k1)] = r[BREV(k1)];
    }
    __syncthreads();                      // W_hi before R_hi
    if (!lo){
#pragma unroll
        for (int n2 = 0; n2 < 16; ++n2) r[n2] = sh8[lr*LSTR + t*16 + (n2 ^ t)];
    }
    fft16<DIR>(r);
}

// Register twiddle for the BARRIER-FREE t-fast path only (p1/p45, where gather
// latency hides the serial chain): r[BREV(k1)] *= w^k1, w = e^{DIR*2pi*i*t/256}.
template<int DIR>
__device__ __forceinline__ void twiddle_reg(vf2 r[16], int t){
    float sn, cn; __sincosf((float)DIR * 0.0245436926f * (float)t, &sn, &cn);
    vf2 w; w.x = cn; w.y = sn;
    vf2 wk = w;
#pragma unroll
    for (int k1 = 1; k1 < 16; ++k1){
        r[BREV(k1)] = cmul(r[BREV(k1)], wk);
        wk = cmul(wk, w);
    }
}

// Intra-wave transpose core for the t-FAST layout (t = tid&15, l = tid>>4):
// each wave holds all 16 t for its 4 l-rows -> transposes are INTRA-WAVE.
// Lines l and l^2 time-share one LDS line in two phases; same-wave DS ops
// execute in issue order -> no s_barrier, but the phases must not be merged/
// reordered: sched_barrier(0) fences them and phase B iterates in reverse.
__device__ __forceinline__ void wave_transpose(vf2 r[16], vf2* shw, int t, int l){
    vf2* base = shw + ((l >> 2)*2 + (l & 1))*LSTR;        // line shared by l and l^2
    if ((l & 2) == 0){                                    // phase A: l_local 0,1
#pragma unroll
        for (int k1 = 0; k1 < 16; ++k1) base[k1*16 + (t ^ k1)] = r[BREV(k1)];
#pragma unroll
        for (int n2 = 0; n2 < 16; ++n2) r[n2] = base[t*16 + (n2 ^ t)];
    }
    __builtin_amdgcn_sched_barrier(0);                    // A-reads issue before B-writes
    if ((l & 2) != 0){                                    // phase B: l_local 2,3 (reverse order)
#pragma unroll
        for (int k1 = 15; k1 >= 0; --k1) base[k1*16 + (t ^ k1)] = r[BREV(k1)];
#pragma unroll
        for (int n2 = 15; n2 >= 0; --n2) r[n2] = base[t*16 + (n2 ^ t)];
    }
}

// Barrier-free mid256 (t-fast) with register twiddles: ZERO __syncthreads.
template<int DIR>
__device__ __forceinline__ void mid256wr(vf2 r[16], vf2* shw, int t, int l){
    fft16<DIR>(r);
    twiddle_reg<DIR>(r, t);
    wave_transpose(r, shw, t, l);
    fft16<DIR>(r);
}

// Strided-axis FFT on PACKED-fp16 data: 16 consecutive x per block, stride S
// elements. Reads idx<NIN (rest structurally zero), writes idx<NOUT scaled by sc.
// 4 barriers total (1 tw + 3 in mid256t).
template<int DIR, int NIN, int NOUT>
__device__ __forceinline__ void fft_strided(unsigned* g, int S, float sc){
    __shared__ vf2 sh8[8*LSTR];
    __shared__ vf2 tw[256];
    int t = threadIdx.x >> 4, l = threadIdx.x & 15;
    vf2 r[16];
    vf2 zero; zero.x = 0.f; zero.y = 0.f;
#pragma unroll
    for (int n1 = 0; n1 < 16; ++n1)
        r[n1] = (n1 < NIN/16) ? uph(g[(size_t)(16*n1 + t)*S + l]) : zero;   // loads issue first
    init_tw(tw, (float)DIR);
    __syncthreads();                                 // tw ready
    mid256t<DIR>(r, sh8, tw, t, l);
#pragma unroll
    for (int k2 = 0; k2 < 16; ++k2)
        if (k2 < NOUT/16) g[(size_t)(t + 16*k2)*S + l] = pkh(r[BREV(k2)]*sc);
}

// P1: read input, val = sqrt(relu(f*gz^2)), zero-pad 128->256, forward FFT along x
// with the half-pixel x-average folded ALGEBRAICALLY:
//   out[k] = FFT( x[n] * 0.5*(1 + e^{+2pi i n/256}) )[k]   (cyclic part)
//   out[128] = 0.5 * sum_n (-1)^n x[n]                      (dropped tap at k=128)
// t-FAST layout, mid256wr, ZERO __syncthreads. Stores fp16-packed A (scale 1).
__global__ void __launch_bounds__(256) k_p1(const float* __restrict__ in, unsigned* __restrict__ A){
    __shared__ vf2 sh8[8*LSTR];
    int tid = threadIdx.x, bid = blockIdx.x;         // v*1024 + z*8 + yc
    int yc = bid & 7, z = (bid >> 3) & 127, v = bid >> 10;
    int t = tid & 15, l = tid >> 4;                  // lanes 0..15 = consecutive x
    float gz = z * (1.0f/127.0f);
    float g2 = gz*gz;
    const float* src = in + (((size_t)(v*128 + z))*128 + yc*16 + l)*128;  // row y=yc*16+l
    float val[8];
#pragma unroll
    for (int n1 = 0; n1 < 8; ++n1) val[n1] = src[16*n1 + t];   // loads issue first
#pragma unroll
    for (int n1 = 0; n1 < 8; ++n1){
        float x = val[n1] * g2;
        val[n1] = x > 0.f ? sqrtf(x) : 0.f;
    }
    // k=128 fix-up: S = sum_n (-1)^n x[n]; sign = (-1)^t. Intra-row butterfly over t.
    float part = ((val[0]+val[1]) + (val[2]+val[3])) + ((val[4]+val[5]) + (val[6]+val[7]));
    part = (t & 1) ? -part : part;
    part += __shfl_xor(part, 1);
    part += __shfl_xor(part, 2);
    part += __shfl_xor(part, 4);
    part += __shfl_xor(part, 8);
    // prefilter (input real): r[n] = x[n] * 0.5*(1+cos, sin), theta = 2pi n/256
    vf2 r[16];
    vf2 zero; zero.x = 0.f; zero.y = 0.f;
#pragma unroll
    for (int n1 = 8; n1 < 16; ++n1) r[n1] = zero;
#pragma unroll
    for (int n1 = 0; n1 < 8; ++n1){
        float sn, cn; __sincosf(0.0245436926f * (float)(16*n1 + t), &sn, &cn);
        r[n1].x = val[n1] * 0.5f * (1.f + cn);
        r[n1].y = val[n1] * 0.5f * sn;
    }
    mid256wr<-1>(r, sh8, t, l);
    if (t == 0){ r[1].x = part*0.5f; r[1].y = 0.f; } // BREV(8)=1 -> X[128], real
    unsigned* dst = A + (size_t)v*VS + (size_t)z*ZSTR + (size_t)(yc*16 + l)*YSTR;
#pragma unroll
    for (int k2 = 0; k2 < 16; ++k2)                  // x = t+16*k2, 16 lanes = 64B
        dst[t + 16*k2] = pkh(r[BREV(k2)]);
}

// P2z: forward FFT along z (before y-FFT: only y<128 columns exist -> half
// traffic). Read z<128, write z<128. In-place, scale 1 (max ~16k, fp16-safe).
__global__ void __launch_bounds__(256) k_p2z(unsigned* __restrict__ A){
    int bid = blockIdx.x;                            // v*2048 + y*16 + xb   (y < 128)
    int xb = bid & 15, y = (bid >> 4) & 127, v = bid >> 11;
    fft_strided<-1,128,128>(A + (size_t)v*VS + (size_t)y*YSTR + xb*16, ZSTR, 1.f);
}

// P3y: forward FFT along y for each z<128 slab (read y<128, write 256).
// Half-pixel y-average folded algebraically (prefilter + k=128 fixup).
// Stores scaled by 2^-6 to keep fp16 in range (worst-case max 32768).
__global__ void __launch_bounds__(256) k_p3y(unsigned* __restrict__ A){
    __shared__ vf2 sh8[8*LSTR];
    __shared__ vf2 tw[256];
    __shared__ vf2 shW[64];                          // per-wave partials of sum (-1)^n x[n]
    const float SC3 = 0.015625f;                     // 2^-6
    int bid = blockIdx.x;                            // v*2048 + z*16 + xb   (z < 128)
    int xb = bid & 15, z = (bid >> 4) & 127, v = bid >> 11;
    unsigned* g = A + (size_t)v*VS + (size_t)z*ZSTR + xb*16;
    int t = threadIdx.x >> 4, l = threadIdx.x & 15;
    vf2 r[16];
    vf2 zero; zero.x = 0.f; zero.y = 0.f;
#pragma unroll
    for (int n1 = 0; n1 < 16; ++n1)
        r[n1] = (n1 < 8) ? uph(g[(size_t)(16*n1 + t)*YSTR + l]) : zero;   // loads issue first

    // alternating-sum partial from RAW inputs: (-1)^n = (-1)^t since 16*n1 even.
    vf2 part = ((r[0]+r[1]) + (r[2]+r[3])) + ((r[4]+r[5]) + (r[6]+r[7]));
    part = part * ((t & 1) ? -1.f : 1.f);
    part.x += __shfl_xor(part.x, 16);                // t ^ 1  (within wave)
    part.y += __shfl_xor(part.y, 16);
    part.x += __shfl_xor(part.x, 32);                // t ^ 2  (within wave)
    part.y += __shfl_xor(part.y, 32);
    if ((t & 3) == 0) shW[(t >> 2)*16 + l] = part;   // one entry per (wave, l)

    // cyclic-average pre-filter: r[n] *= 0.5*(1 + e^{+2pi i n/256})
#pragma unroll
    for (int n1 = 0; n1 < 8; ++n1){
        float sn, cn; __sincosf(0.0245436926f * (float)(16*n1 + t), &sn, &cn);
        vf2 c; c.x = 0.5f*(1.f + cn); c.y = 0.5f*sn;
        r[n1] = cmul(r[n1], c);
    }

    init_tw(tw, -1.f);
    __syncthreads();                                 // tw + shW ready
    mid256t<-1>(r, sh8, tw, t, l);

    if (t == 0){                                     // k = 128 fix-up (t=0, k2=8)
        vf2 S = (shW[l] + shW[16 + l]) + (shW[32 + l] + shW[48 + l]);
        r[BREV(8)] = S * 0.5f;
    }
#pragma unroll
    for (int k2 = 0; k2 < 16; ++k2)                  // direct store: 16 x-lanes = 64B
        g[(size_t)(t + 16*k2)*YSTR + l] = pkh(r[BREV(k2)]*SC3);
}

// P45: fused Stolt z-resample (2 taps) + x-iFFT. Direct global->register gather
// (t=tid&15 lane-fast) and direct register->global store. t-fast + register
// twiddles -> ZERO barriers. Gather-BW-bound (r5); fp16 halves its bytes.
__global__ void __launch_bounds__(256) k_p45(const unsigned* __restrict__ A, unsigned* __restrict__ B){
    __shared__ vf2 sh8[8*LSTR];
    int tid = threadIdx.x, bid = blockIdx.x;         // v*2048 + zn*16 + yc
    int yc = bid & 15, zn = (bid >> 4) & 127, v = bid >> 11;
    const unsigned* Av = A + (size_t)v*VS;
    int t = tid & 15, l = tid >> 4;                  // lanes 0..15 = consecutive x
    int yn = yc*16 + l;
    float gy = (yn < 128 ? yn : yn - 256) * (1.0f/128.0f);
    float gz = zn * (1.0f/128.0f);
    float c2 = 0.1024f*gy*gy + gz*gz;
    unsigned rowoff = (unsigned)yn*YSTR;
    vf2 r[16];
#pragma unroll
    for (int n1 = 0; n1 < 16; ++n1){
        int xn = 16*n1 + t;
        float gx = (xn < 128 ? xn : xn - 256) * (1.0f/128.0f);
        float s2 = c2 + 0.1024f*gx*gx;
        float rs = __builtin_amdgcn_rsqf(s2 + 1e-12f);   // 1/gznew; zn==0 row -> wf=0
        float gznew = s2 * rs;
        float pz = gznew*128.0f + 127.5f;
        int zi = (int)pz;                                // trunc == floor (pz>0)
        float dz = pz - (float)zi;
        int zp0 = zi - 128;                              // natural z of first tap
        float wf = gz * rs;                              // gz/gznew
        float w0 = (((unsigned)zp0     < 128u) ? (1.0f - dz) : 0.f) * wf;
        float w1 = (((unsigned)(zp0+1) < 128u) ? dz : 0.f) * wf;
        vf2 v0 = uph(Av[(size_t)((unsigned)(zp0 & 127) * ZSTR) + rowoff + xn]);
        vf2 v1 = uph(Av[(size_t)((unsigned)((zp0 + 1) & 127) * ZSTR) + rowoff + xn]);
        r[n1] = v0*w0 + v1*w1;
    }
    mid256wr<1>(r, sh8, t, l);
    unsigned* dst = B + (size_t)v*VSB + (size_t)zn*BZS + (size_t)yn*BYS;
#pragma unroll
    for (int k2 = 0; k2 < 8; ++k2)                   // x = t+16*k2 < 128, coalesced
        dst[t + 16*k2] = pkh(r[BREV(k2)]);
}

// P6: inverse FFT along y on packed B (x<128). Read 256 y, write y<128.
// Stores scaled by 2^-8 (fp16 range: worst-case max 32768).
__global__ void __launch_bounds__(256) k_p6(unsigned* __restrict__ B){
    int bid = blockIdx.x;                            // v*1024 + zn*8 + xb
    int xb = bid & 7, zn = (bid >> 3) & 127, v = bid >> 10;
    fft_strided<1,256,128>(B + (size_t)v*VSB + (size_t)zn*BZS + xb*16, BYS, 0.00390625f);
}

// P7: inverse FFT along z for y<128, x<128 on packed B. Read zn<128,
// output real part scaled by residual 2^-10 (total = 2^-24 = 1/256^3).
__global__ void __launch_bounds__(256) k_p7(const unsigned* __restrict__ B, float* __restrict__ out){
    __shared__ vf2 sh8[8*LSTR];
    __shared__ vf2 tw[256];
    int bid = blockIdx.x;                            // v*1024 + y*8 + xb
    int xb = bid & 7, y = (bid >> 3) & 127, v = bid >> 10;
    const unsigned* g = B + (size_t)v*VSB + (size_t)y*BYS + xb*16;
    int t = threadIdx.x >> 4, l = threadIdx.x & 15;
    vf2 r[16];
    vf2 zero; zero.x = 0.f; zero.y = 0.f;
#pragma unroll
    for (int n1 = 0; n1 < 16; ++n1)
        r[n1] = (n1 < 8) ? uph(g[(size_t)(16*n1 + t)*BZS + l]) : zero;
    init_tw(tw, 1.f);
    __syncthreads();
    mid256t<1>(r, sh8, tw, t, l);
    const float sc = 9.765625e-4f;                   // 2^-10
    float* dst = out + ((size_t)(v*128)*128 + y)*128 + xb*16 + l;
#pragma unroll
    for (int k2 = 0; k2 < 8; ++k2)                   // k = t + 16*k2 < 128
        dst[(size_t)(t + 16*k2)*16384] = r[BREV(k2)].x * sc;
}

extern "C" void kernel_launch(void* const* d_in, const int* in_sizes, int n_in,
                              void* d_out, int out_size, void* d_ws, size_t ws_size,
                              hipStream_t stream){
    const float* in = (const float*)d_in[0];
    float* out = (float*)d_out;
    unsigned* A = (unsigned*)d_ws;         // 67 MB (fp16-packed)
    unsigned* B = A + 2*VS;                // 33.5 MB (fp16-packed)
    k_p1 <<< 2048, 256, 0, stream>>>(in, A);
    k_p2z<<< 4096, 256, 0, stream>>>(A);   // z-FFT first: y<128 -> half traffic
    k_p3y<<< 4096, 256, 0, stream>>>(A);
    k_p45<<< 4096, 256, 0, stream>>>(A, B);
    k_p6 <<< 2048, 256, 0, stream>>>(B);
    k_p7 <<< 2048, 256, 0, stream>>>(B, out);
}

// Round 8
// 183.338 us; speedup vs baseline: 1.0976x; 1.0089x over previous
//
#include <hip/hip_runtime.h>

// Geometry: M=N=128, padded S=256. Two volumes (b*d=2).
// A: [v][z<128][y:256][x:256] complex FP16-PACKED (uint32 = re:f16 | im:f16<<16) = 67 MB.
// B (packed): [v][z<128][y:256][x<128] complex fp16 = 33.5 MB.
// Per-stage folded scales keep fp16 in range (applied at LOAD/prefilter so the
// fp16 LDS transpose midpoints (<=16x input) also stay in range):
//   p1 x1 (<=128) -> p2z x1 (mid<=2k) -> p3y x2^-6 in prefilter (mid<=4k)
//   -> p45 x1 -> p6 x2^-8 at load (mid<=4k) -> p7 x2^-10 at load (mid<=1k)
//   == old 1/256^3 total.
static constexpr size_t VS   = 8388608;  // 128*256*256 per volume (A), elements
static constexpr int    ZSTR = 65536;    // 256*256
static constexpr int    YSTR = 256;
static constexpr size_t VSB  = 4194304;  // 128*256*128 per volume (B), elements
static constexpr int    BZS  = 32768;    // 256*128
static constexpr int    BYS  = 128;
static constexpr int    LSTR = 261;      // LDS line stride; 261 mod 32 = 5 spreads banks

typedef float vf2 __attribute__((ext_vector_type(2)));       // complex fp32 in regs
typedef _Float16 h2 __attribute__((ext_vector_type(2)));     // packed fp16 pair

// fp16 pack/unpack (v_cvt_f16_f32 RNE / v_cvt_f32_f16)
__device__ __forceinline__ unsigned pkh(vf2 a){
    h2 h; h.x = (_Float16)a.x; h.y = (_Float16)a.y;
    return __builtin_bit_cast(unsigned, h);
}
__device__ __forceinline__ vf2 uph(unsigned u){
    h2 h = __builtin_bit_cast(h2, u);
    vf2 r; r.x = (float)h.x; r.y = (float)h.y; return r;
}

__device__ __forceinline__ vf2 cmul(vf2 a, vf2 b){
    vf2 asw; asw.x = -a.y; asw.y = a.x;       // i*a
    return a*b.x + asw*b.y;                   // pk_mul + pk_fma
}

constexpr int BREV(int k){ return ((k&1)<<3)|((k&2)<<1)|((k&4)>>1)|((k&8)>>3); }

// Butterfly: a' = a+b; b' = (a-b) rotated by (c,s). Packed VOP3P.
__device__ __forceinline__ void bf(vf2& a, vf2& b, float c, float s){
    vf2 sum = a + b;
    vf2 dif = a - b;
    vf2 dsw; dsw.x = -dif.y; dsw.y = dif.x;   // i*dif
    b = dif*c + dsw*s;
    a = sum;
}

// Fully-unrolled 16-pt DIF FFT, natural input, bit-reversed output: X[k] = r[BREV(k)].
template<int DIR>
__device__ __forceinline__ void fft16(vf2 r[16]){
    constexpr float D = (float)DIR;
    constexpr float C16[8] = {1.f, 0.92387953f, 0.70710678f, 0.38268343f, 0.f, -0.38268343f, -0.70710678f, -0.92387953f};
    constexpr float S16[8] = {0.f, 0.38268343f, 0.70710678f, 0.92387953f, 1.f, 0.92387953f, 0.70710678f, 0.38268343f};
#pragma unroll
    for (int j = 0; j < 8; ++j) bf(r[j], r[j+8], C16[j], D*S16[j]);
    constexpr float C8[4] = {1.f, 0.70710678f, 0.f, -0.70710678f};
    constexpr float S8[4] = {0.f, 0.70710678f, 1.f, 0.70710678f};
#pragma unroll
    for (int g = 0; g < 16; g += 8)
#pragma unroll
        for (int j = 0; j < 4; ++j) bf(r[g+j], r[g+j+4], C8[j], D*S8[j]);
#pragma unroll
    for (int g = 0; g < 16; g += 4){
        bf(r[g],   r[g+2], 1.f, 0.f);
        bf(r[g+1], r[g+3], 0.f, D);
    }
#pragma unroll
    for (int g = 0; g < 16; g += 2) bf(r[g], r[g+1], 1.f, 0.f);
}

// Per-block twiddle table: tw[a*16+b] = e^{DIR*2pi*i*a*b/256}.
// Caller must barrier between init and first use. (Table beats a register
// recurrence on t-slow kernels: serial 15-cmul chain regressed in r5.)
__device__ __forceinline__ void init_tw(vf2* tw, float dir){
    int tid = threadIdx.x;
    float ang = dir * 0.0245436926f * (float)((tid >> 4)*(tid & 15));
    float s, c; __sincosf(ang, &s, &c);
    vf2 w; w.x = c; w.y = s;
    tw[tid] = w;
}

// TWO-COLUMN middle of four-step 256-pt FFT, t-SLOW layout (t = tid>>4).
// Each thread carries 2 x-columns; the 16x16 transposes go through a PACKED
// fp16 LDS buffer (16 lines x u32 = 16.7 KB, same footprint as the old fp32
// 8-line buffer). 3 barriers, two passes (l<8 then l>=8), 16 lines per pass.
// Range: inputs must be pre-scaled so |mid| <= 16*|in| < 65504.
template<int DIR>
__device__ __forceinline__ void mid256t2(vf2 r[2][16], unsigned* shp, const vf2* tw, int t, int l){
#pragma unroll
    for (int c = 0; c < 2; ++c) fft16<DIR>(r[c]);
#pragma unroll
    for (int k1 = 1; k1 < 16; ++k1){
        vf2 w = tw[k1*16 + t];                        // broadcast across l
        r[0][BREV(k1)] = cmul(r[0][BREV(k1)], w);
        r[1][BREV(k1)] = cmul(r[1][BREV(k1)], w);
    }
    int lr = l & 7;
    bool lo = (l < 8);
    if (lo){
#pragma unroll
        for (int c = 0; c < 2; ++c)
#pragma unroll
            for (int k1 = 0; k1 < 16; ++k1)
                shp[(lr*2 + c)*LSTR + k1*16 + (t ^ k1)] = pkh(r[c][BREV(k1)]);
    }
    __syncthreads();                      // W_lo before R_lo
    if (lo){
#pragma unroll
        for (int c = 0; c < 2; ++c)
#pragma unroll
            for (int n2 = 0; n2 < 16; ++n2)
                r[c][n2] = uph(shp[(lr*2 + c)*LSTR + t*16 + (n2 ^ t)]);
    }
    __syncthreads();                      // R_lo before W_hi (same lines)
    if (!lo){
#pragma unroll
        for (int c = 0; c < 2; ++c)
#pragma unroll
            for (int k1 = 0; k1 < 16; ++k1)
                shp[(lr*2 + c)*LSTR + k1*16 + (t ^ k1)] = pkh(r[c][BREV(k1)]);
    }
    __syncthreads();                      // W_hi before R_hi
    if (!lo){
#pragma unroll
        for (int c = 0; c < 2; ++c)
#pragma unroll
            for (int n2 = 0; n2 < 16; ++n2)
                r[c][n2] = uph(shp[(lr*2 + c)*LSTR + t*16 + (n2 ^ t)]);
    }
#pragma unroll
    for (int c = 0; c < 2; ++c) fft16<DIR>(r[c]);
}

// Register twiddle for the BARRIER-FREE t-fast path only (p1/p45, where gather
// latency hides the serial chain): r[BREV(k1)] *= w^k1, w = e^{DIR*2pi*i*t/256}.
template<int DIR>
__device__ __forceinline__ void twiddle_reg(vf2 r[16], int t){
    float sn, cn; __sincosf((float)DIR * 0.0245436926f * (float)t, &sn, &cn);
    vf2 w; w.x = cn; w.y = sn;
    vf2 wk = w;
#pragma unroll
    for (int k1 = 1; k1 < 16; ++k1){
        r[BREV(k1)] = cmul(r[BREV(k1)], wk);
        wk = cmul(wk, w);
    }
}

// Intra-wave transpose core for the t-FAST layout (t = tid&15, l = tid>>4):
// transposes are INTRA-WAVE; lines l and l^2 time-share one LDS line in two
// phases; same-wave DS ops execute in issue order -> no s_barrier, but the
// phases must not be merged/reordered: sched_barrier(0) fences them and
// phase B iterates in reverse.
__device__ __forceinline__ void wave_transpose(vf2 r[16], vf2* shw, int t, int l){
    vf2* base = shw + ((l >> 2)*2 + (l & 1))*LSTR;        // line shared by l and l^2
    if ((l & 2) == 0){                                    // phase A: l_local 0,1
#pragma unroll
        for (int k1 = 0; k1 < 16; ++k1) base[k1*16 + (t ^ k1)] = r[BREV(k1)];
#pragma unroll
        for (int n2 = 0; n2 < 16; ++n2) r[n2] = base[t*16 + (n2 ^ t)];
    }
    __builtin_amdgcn_sched_barrier(0);                    // A-reads issue before B-writes
    if ((l & 2) != 0){                                    // phase B: l_local 2,3 (reverse order)
#pragma unroll
        for (int k1 = 15; k1 >= 0; --k1) base[k1*16 + (t ^ k1)] = r[BREV(k1)];
#pragma unroll
        for (int n2 = 15; n2 >= 0; --n2) r[n2] = base[t*16 + (n2 ^ t)];
    }
}

// Barrier-free mid256 (t-fast) with register twiddles: ZERO __syncthreads.
template<int DIR>
__device__ __forceinline__ void mid256wr(vf2 r[16], vf2* shw, int t, int l){
    fft16<DIR>(r);
    twiddle_reg<DIR>(r, t);
    wave_transpose(r, shw, t, l);
    fft16<DIR>(r);
}

// TWO-COLUMN strided-axis FFT on packed fp16: 32 consecutive x per block
// (2 per thread, uint2 = 128B/16 lanes). Reads idx<NIN (rest zero) scaled by
// insc at load (fold point for range safety); writes idx<NOUT unscaled.
template<int DIR, int NIN, int NOUT>
__device__ __forceinline__ void fft_strided2(unsigned* g, int S, float insc){
    __shared__ unsigned shp[16*LSTR];
    __shared__ vf2 tw[256];
    int t = threadIdx.x >> 4, l = threadIdx.x & 15;
    vf2 r[2][16];
    vf2 zero; zero.x = 0.f; zero.y = 0.f;
#pragma unroll
    for (int n1 = 0; n1 < 16; ++n1){
        if (n1 < NIN/16){
            uint2 ld = *reinterpret_cast<const uint2*>(&g[(size_t)(16*n1 + t)*S + 2*l]);
            r[0][n1] = uph(ld.x)*insc;
            r[1][n1] = uph(ld.y)*insc;
        } else { r[0][n1] = zero; r[1][n1] = zero; }
    }
    init_tw(tw, (float)DIR);
    __syncthreads();                                 // tw ready
    mid256t2<DIR>(r, shp, tw, t, l);
#pragma unroll
    for (int k2 = 0; k2 < 16; ++k2)
        if (k2 < NOUT/16){
            uint2 st; st.x = pkh(r[0][BREV(k2)]); st.y = pkh(r[1][BREV(k2)]);
            *reinterpret_cast<uint2*>(&g[(size_t)(t + 16*k2)*S + 2*l]) = st;
        }
}

// P1: read input, val = sqrt(relu(f*gz^2)), zero-pad 128->256, forward FFT along x
// with the half-pixel x-average folded ALGEBRAICALLY:
//   out[k] = FFT( x[n] * 0.5*(1 + e^{+2pi i n/256}) )[k]   (cyclic part)
//   out[128] = 0.5 * sum_n (-1)^n x[n]                      (dropped tap at k=128)
// t-FAST layout, mid256wr, ZERO __syncthreads. Stores fp16-packed A (scale 1).
__global__ void __launch_bounds__(256) k_p1(const float* __restrict__ in, unsigned* __restrict__ A){
    __shared__ vf2 sh8[8*LSTR];
    int tid = threadIdx.x, bid = blockIdx.x;         // v*1024 + z*8 + yc
    int yc = bid & 7, z = (bid >> 3) & 127, v = bid >> 10;
    int t = tid & 15, l = tid >> 4;                  // lanes 0..15 = consecutive x
    float gz = z * (1.0f/127.0f);
    float g2 = gz*gz;
    const float* src = in + (((size_t)(v*128 + z))*128 + yc*16 + l)*128;  // row y=yc*16+l
    float val[8];
#pragma unroll
    for (int n1 = 0; n1 < 8; ++n1) val[n1] = src[16*n1 + t];   // loads issue first
#pragma unroll
    for (int n1 = 0; n1 < 8; ++n1){
        float x = val[n1] * g2;
        val[n1] = x > 0.f ? sqrtf(x) : 0.f;
    }
    // k=128 fix-up: S = sum_n (-1)^n x[n]; sign = (-1)^t. Intra-row butterfly over t.
    float part = ((val[0]+val[1]) + (val[2]+val[3])) + ((val[4]+val[5]) + (val[6]+val[7]));
    part = (t & 1) ? -part : part;
    part += __shfl_xor(part, 1);
    part += __shfl_xor(part, 2);
    part += __shfl_xor(part, 4);
    part += __shfl_xor(part, 8);
    // prefilter (input real): r[n] = x[n] * 0.5*(1+cos, sin), theta = 2pi n/256
    vf2 r[16];
    vf2 zero; zero.x = 0.f; zero.y = 0.f;
#pragma unroll
    for (int n1 = 8; n1 < 16; ++n1) r[n1] = zero;
#pragma unroll
    for (int n1 = 0; n1 < 8; ++n1){
        float sn, cn; __sincosf(0.0245436926f * (float)(16*n1 + t), &sn, &cn);
        r[n1].x = val[n1] * 0.5f * (1.f + cn);
        r[n1].y = val[n1] * 0.5f * sn;
    }
    mid256wr<-1>(r, sh8, t, l);
    if (t == 0){ r[1].x = part*0.5f; r[1].y = 0.f; } // BREV(8)=1 -> X[128], real
    unsigned* dst = A + (size_t)v*VS + (size_t)z*ZSTR + (size_t)(yc*16 + l)*YSTR;
#pragma unroll
    for (int k2 = 0; k2 < 16; ++k2)                  // x = t+16*k2, 16 lanes = 64B
        dst[t + 16*k2] = pkh(r[BREV(k2)]);
}

// P2z: forward FFT along z (before y-FFT: only y<128 columns exist -> half
// traffic). Read z<128, write z<128. In-place, scale 1 (mid<=2k, fp16-safe).
// 32 x per block (2/thread).
__global__ void __launch_bounds__(256) k_p2z(unsigned* __restrict__ A){
    int bid = blockIdx.x;                            // v*1024 + y*8 + xb   (y < 128)
    int xb = bid & 7, y = (bid >> 3) & 127, v = bid >> 10;
    fft_strided2<-1,128,128>(A + (size_t)v*VS + (size_t)y*YSTR + xb*32, ZSTR, 1.f);
}

// P3y: forward FFT along y for each z<128 slab (read y<128, write 256).
// Half-pixel y-average folded algebraically; 2^-6 scale folded into the
// PREFILTER so the fp16 LDS transpose midpoints stay in range (<=4k).
// 32 x per block (2/thread).
__global__ void __launch_bounds__(256) k_p3y(unsigned* __restrict__ A){
    __shared__ unsigned shp[16*LSTR];
    __shared__ vf2 tw[256];
    __shared__ vf2 shW[128];                         // per-wave partials, 2 cols
    const float SC3 = 0.015625f;                     // 2^-6
    int bid = blockIdx.x;                            // v*1024 + z*8 + xb   (z < 128)
    int xb = bid & 7, z = (bid >> 3) & 127, v = bid >> 10;
    unsigned* g = A + (size_t)v*VS + (size_t)z*ZSTR + xb*32;
    int t = threadIdx.x >> 4, l = threadIdx.x & 15;
    vf2 r[2][16];
    vf2 zero; zero.x = 0.f; zero.y = 0.f;
#pragma unroll
    for (int n1 = 0; n1 < 16; ++n1){
        if (n1 < 8){
            uint2 ld = *reinterpret_cast<const uint2*>(&g[(size_t)(16*n1 + t)*YSTR + 2*l]);
            r[0][n1] = uph(ld.x);
            r[1][n1] = uph(ld.y);
        } else { r[0][n1] = zero; r[1][n1] = zero; }
    }
    // alternating-sum partial from RAW inputs: (-1)^n = (-1)^t since 16*n1 even.
#pragma unroll
    for (int c = 0; c < 2; ++c){
        vf2 part = ((r[c][0]+r[c][1]) + (r[c][2]+r[c][3])) + ((r[c][4]+r[c][5]) + (r[c][6]+r[c][7]));
        part = part * ((t & 1) ? -1.f : 1.f);
        part.x += __shfl_xor(part.x, 16);            // t ^ 1  (within wave)
        part.y += __shfl_xor(part.y, 16);
        part.x += __shfl_xor(part.x, 32);            // t ^ 2  (within wave)
        part.y += __shfl_xor(part.y, 32);
        if ((t & 3) == 0) shW[(t >> 2)*32 + 2*l + c] = part;  // per (wave, col)
    }
    // cyclic-average pre-filter x SC3: r[n] *= SC3*0.5*(1 + e^{+2pi i n/256})
#pragma unroll
    for (int n1 = 0; n1 < 8; ++n1){
        float sn, cn; __sincosf(0.0245436926f * (float)(16*n1 + t), &sn, &cn);
        vf2 c; c.x = SC3*0.5f*(1.f + cn); c.y = SC3*0.5f*sn;
        r[0][n1] = cmul(r[0][n1], c);
        r[1][n1] = cmul(r[1][n1], c);
    }
    init_tw(tw, -1.f);
    __syncthreads();                                 // tw + shW ready
    mid256t2<-1>(r, shp, tw, t, l);
    if (t == 0){                                     // k = 128 fix-up (t=0, k2=8)
#pragma unroll
        for (int c = 0; c < 2; ++c){
            vf2 S = (shW[2*l + c] + shW[32 + 2*l + c]) + (shW[64 + 2*l + c] + shW[96 + 2*l + c]);
            r[c][BREV(8)] = S * (0.5f*SC3);
        }
    }
#pragma unroll
    for (int k2 = 0; k2 < 16; ++k2){                 // uint2 store: 16 lanes = 128B
        uint2 st; st.x = pkh(r[0][BREV(k2)]); st.y = pkh(r[1][BREV(k2)]);
        *reinterpret_cast<uint2*>(&g[(size_t)(t + 16*k2)*YSTR + 2*l]) = st;
    }
}

// P45: fused Stolt z-resample (2 taps) + x-iFFT. Direct global->register gather
// (t=tid&15 lane-fast) and direct register->global store. t-fast + register
// twiddles -> ZERO barriers. Gather-BW-bound (r5); unchanged this round.
__global__ void __launch_bounds__(256) k_p45(const unsigned* __restrict__ A, unsigned* __restrict__ B){
    __shared__ vf2 sh8[8*LSTR];
    int tid = threadIdx.x, bid = blockIdx.x;         // v*2048 + zn*16 + yc
    int yc = bid & 15, zn = (bid >> 4) & 127, v = bid >> 11;
    const unsigned* Av = A + (size_t)v*VS;
    int t = tid & 15, l = tid >> 4;                  // lanes 0..15 = consecutive x
    int yn = yc*16 + l;
    float gy = (yn < 128 ? yn : yn - 256) * (1.0f/128.0f);
    float gz = zn * (1.0f/128.0f);
    float c2 = 0.1024f*gy*gy + gz*gz;
    unsigned rowoff = (unsigned)yn*YSTR;
    vf2 r[16];
#pragma unroll
    for (int n1 = 0; n1 < 16; ++n1){
        int xn = 16*n1 + t;
        float gx = (xn < 128 ? xn : xn - 256) * (1.0f/128.0f);
        float s2 = c2 + 0.1024f*gx*gx;
        float rs = __builtin_amdgcn_rsqf(s2 + 1e-12f);   // 1/gznew; zn==0 row -> wf=0
        float gznew = s2 * rs;
        float pz = gznew*128.0f + 127.5f;
        int zi = (int)pz;                                // trunc == floor (pz>0)
        float dz = pz - (float)zi;
        int zp0 = zi - 128;                              // natural z of first tap
        float wf = gz * rs;                              // gz/gznew
        float w0 = (((unsigned)zp0     < 128u) ? (1.0f - dz) : 0.f) * wf;
        float w1 = (((unsigned)(zp0+1) < 128u) ? dz : 0.f) * wf;
        vf2 v0 = uph(Av[(size_t)((unsigned)(zp0 & 127) * ZSTR) + rowoff + xn]);
        vf2 v1 = uph(Av[(size_t)((unsigned)((zp0 + 1) & 127) * ZSTR) + rowoff + xn]);
        r[n1] = v0*w0 + v1*w1;
    }
    mid256wr<1>(r, sh8, t, l);
    unsigned* dst = B + (size_t)v*VSB + (size_t)zn*BZS + (size_t)yn*BYS;
#pragma unroll
    for (int k2 = 0; k2 < 8; ++k2)                   // x = t+16*k2 < 128, coalesced
        dst[t + 16*k2] = pkh(r[BREV(k2)]);
}

// P6: inverse FFT along y on packed B (x<128). Read 256 y, write y<128.
// 2^-8 scale folded at LOAD (fp16 LDS mid <=4k). 32 x per block (2/thread).
__global__ void __launch_bounds__(256) k_p6(unsigned* __restrict__ B){
    int bid = blockIdx.x;                            // v*512 + zn*4 + xb
    int xb = bid & 3, zn = (bid >> 2) & 127, v = bid >> 9;
    fft_strided2<1,256,128>(B + (size_t)v*VSB + (size_t)zn*BZS + xb*32, BYS, 0.00390625f);
}

// P7: inverse FFT along z for y<128, x<128 on packed B. Read zn<128 scaled by
// residual 2^-10 at load (total = 2^-24 = 1/256^3), write fp32 real out as
// float2 (2 adjacent x). 32 x per block (2/thread).
__global__ void __launch_bounds__(256) k_p7(const unsigned* __restrict__ B, float* __restrict__ out){
    __shared__ unsigned shp[16*LSTR];
    __shared__ vf2 tw[256];
    const float sc = 9.765625e-4f;                   // 2^-10
    int bid = blockIdx.x;                            // v*512 + y*4 + xb
    int xb = bid & 3, y = (bid >> 2) & 127, v = bid >> 9;
    const unsigned* g = B + (size_t)v*VSB + (size_t)y*BYS + xb*32;
    int t = threadIdx.x >> 4, l = threadIdx.x & 15;
    vf2 r[2][16];
    vf2 zero; zero.x = 0.f; zero.y = 0.f;
#pragma unroll
    for (int n1 = 0; n1 < 16; ++n1){
        if (n1 < 8){
            uint2 ld = *reinterpret_cast<const uint2*>(&g[(size_t)(16*n1 + t)*BZS + 2*l]);
            r[0][n1] = uph(ld.x)*sc;
            r[1][n1] = uph(ld.y)*sc;
        } else { r[0][n1] = zero; r[1][n1] = zero; }
    }
    init_tw(tw, 1.f);
    __syncthreads();
    mid256t2<1>(r, shp, tw, t, l);
    float* dst = out + ((size_t)(v*128)*128 + y)*128 + xb*32 + 2*l;
#pragma unroll
    for (int k2 = 0; k2 < 8; ++k2){                  // k = t + 16*k2 < 128
        float2 st; st.x = r[0][BREV(k2)].x; st.y = r[1][BREV(k2)].x;
        *reinterpret_cast<float2*>(&dst[(size_t)(t + 16*k2)*16384]) = st;
    }
}

extern "C" void kernel_launch(void* const* d_in, const int* in_sizes, int n_in,
                              void* d_out, int out_size, void* d_ws, size_t ws_size,
                              hipStream_t stream){
    const float* in = (const float*)d_in[0];
    float* out = (float*)d_out;
    unsigned* A = (unsigned*)d_ws;         // 67 MB (fp16-packed)
    unsigned* B = A + 2*VS;                // 33.5 MB (fp16-packed)
    k_p1 <<< 2048, 256, 0, stream>>>(in, A);
    k_p2z<<< 2048, 256, 0, stream>>>(A);   // z-FFT first: y<128 -> half traffic
    k_p3y<<< 2048, 256, 0, stream>>>(A);
    k_p45<<< 4096, 256, 0, stream>>>(A, B);
    k_p6 <<< 1024, 256, 0, stream>>>(B);
    k_p7 <<< 1024, 256, 0, stream>>>(B, out);
}